// Round 7
// baseline (241.293 us; speedup 1.0000x reference)
//
#include <hip/hip_runtime.h>
#include <hip/hip_bf16.h>

#define NQ 4096
#define NK 8192
#define NSPLIT 8
#define KSPAN (NK / NSPLIT)
#define BK 64
#define PST 72

// 0.125 (1/sqrt(64)) * log2(e): scores in log2 domain; no max subtraction needed
// (|S| <= ~14 in log2 domain, exp2 can't overflow; scale cancels in O/l)
#define QSCALE 0.1803368801111204f

typedef short v8s __attribute__((ext_vector_type(8)));
typedef float v4f __attribute__((ext_vector_type(4)));

static __device__ __forceinline__ unsigned short f2bf(float f) {
    unsigned int u = __float_as_uint(f);
    u = (u + 0x7FFFu + ((u >> 16) & 1u)) >> 16;
    return (unsigned short)u;
}
static __device__ __forceinline__ float bf2f(unsigned short h) {
    return __uint_as_float(((unsigned int)h) << 16);
}
static __device__ __forceinline__ unsigned int pkbf(float a, float b) {
    union { __hip_bfloat162 h; unsigned int u; } cv;
    cv.h = __float22bfloat162_rn(make_float2(a, b));
    return cv.u;
}
static __device__ __forceinline__ void split8(const float* a, v8s& hi, v8s& lo) {
#pragma unroll
    for (int j = 0; j < 8; ++j) {
        unsigned short h = f2bf(a[j]);
        hi[j] = (short)h;
        lo[j] = (short)f2bf(a[j] - bf2f(h));
    }
}
// gather a W^T[col][k0..k0+7] B-fragment from fp32 W[k][col] (ld=256), hi/lo planes
static __device__ __forceinline__ void wgather(const float* __restrict__ W,
                                               int k0, int col, v8s& wh, v8s& wl) {
    float wv[8];
#pragma unroll
    for (int j = 0; j < 8; ++j) wv[j] = W[(size_t)(k0 + j) * 256 + col];
    split8(wv, wh, wl);
}
// async global->LDS, 16B/lane; dest = uniform base + lane*16
static __device__ __forceinline__ void dma16(const unsigned short* g, unsigned short* l) {
    __builtin_amdgcn_global_load_lds(
        (const __attribute__((address_space(1))) unsigned int*)(const void*)g,
        (__attribute__((address_space(3))) unsigned int*)(void*)l, 16, 0, 0);
}

// ---- fused QKV projection, inline W split, 32 rows/block (st=2)
// grid 640: b<128 Q, b<384 K, else V. wave = 64 output cols (= head).
__global__ __launch_bounds__(256) void qkv_kernel(
    const float* __restrict__ query, const float* __restrict__ key,
    const float* __restrict__ value,
    const float* __restrict__ Wq, const float* __restrict__ Wk,
    const float* __restrict__ Wv,
    const float* __restrict__ bq, const float* __restrict__ bk,
    const float* __restrict__ bv,
    unsigned short* __restrict__ Qb, unsigned short* __restrict__ Kb,
    unsigned short* __restrict__ Vt, const int* __restrict__ nexp)
{
    const int b = blockIdx.x;
    const int t = threadIdx.x, w = t >> 6, lane = t & 63;
    const int quad = lane >> 4, l16 = lane & 15;
    const int colbase = w * 64;

    if (b < 128) {
        // ---- Q: KD=256, 32 rows
        const int n0 = b * 32;
        v4f acc[2][4];
#pragma unroll
        for (int st = 0; st < 2; ++st)
#pragma unroll
            for (int ct = 0; ct < 4; ++ct) {
                const float bb = bq[colbase + ct * 16 + l16];
                acc[st][ct] = v4f{bb, bb, bb, bb};
            }
#pragma unroll
        for (int k0 = 0; k0 < 256; k0 += 32) {
            v8s ah[2], al[2];
#pragma unroll
            for (int st = 0; st < 2; ++st) {
                float av[8];
                const float* ar = query + (size_t)(n0 + st * 16 + l16) * 256 + k0 + quad * 8;
                *(float4*)av = *(const float4*)ar;
                *(float4*)(av + 4) = *(const float4*)(ar + 4);
                split8(av, ah[st], al[st]);
            }
#pragma unroll
            for (int ct = 0; ct < 4; ++ct) {
                v8s wh, wl;
                wgather(Wq, k0 + quad * 8, colbase + ct * 16 + l16, wh, wl);
#pragma unroll
                for (int st = 0; st < 2; ++st) {
                    acc[st][ct] = __builtin_amdgcn_mfma_f32_16x16x32_bf16(al[st], wh, acc[st][ct], 0, 0, 0);
                    acc[st][ct] = __builtin_amdgcn_mfma_f32_16x16x32_bf16(ah[st], wl, acc[st][ct], 0, 0, 0);
                    acc[st][ct] = __builtin_amdgcn_mfma_f32_16x16x32_bf16(ah[st], wh, acc[st][ct], 0, 0, 0);
                }
            }
        }
#pragma unroll
        for (int ct = 0; ct < 4; ++ct) {
            const int d = ct * 16 + l16;
            const int j = d >> 1;
            const float freq = exp2f(-(float)(j & 15) * 1.66096404744368f);
            const bool isx = (j < 16), odd = (d & 1);
#pragma unroll
            for (int st = 0; st < 2; ++st)
#pragma unroll
                for (int r = 0; r < 4; ++r) {
                    const int p = n0 + st * 16 + quad * 4 + r;
                    const float tpos = isx ? (float)(p & 63) : (float)(p >> 6);
                    float sn, cs;
                    __sincosf(tpos * freq, &sn, &cs);
                    const float x = acc[st][ct][r];
                    const float xp = __shfl_xor(x, 1, 64);
                    const float y = odd ? fmaf(x, cs, xp * sn) : fmaf(x, cs, -xp * sn);
                    Qb[((size_t)(w * NQ + p) << 6) + d] = f2bf(y * QSCALE);
                }
        }
    } else {
        const bool isK = (b < 384);
        const int n0 = (isK ? (b - 128) : (b - 384)) * 32;
        const float* X = isK ? key : value;
        const float* W = isK ? Wk : Wv;
        const float* bias = isK ? bk : bv;
        v4f acc[2][4];
#pragma unroll
        for (int st = 0; st < 2; ++st)
#pragma unroll
            for (int ct = 0; ct < 4; ++ct) {
                const float bb = bias[colbase + ct * 16 + l16];
                acc[st][ct] = v4f{bb, bb, bb, bb};
            }
#pragma unroll
        for (int k0 = 0; k0 < 64; k0 += 32) {
            v8s ah[2], al[2];
#pragma unroll
            for (int st = 0; st < 2; ++st) {
                float av[8];
                const float* ar = X + (size_t)(n0 + st * 16 + l16) * 64 + k0 + quad * 8;
                *(float4*)av = *(const float4*)ar;
                *(float4*)(av + 4) = *(const float4*)(ar + 4);
                split8(av, ah[st], al[st]);
            }
#pragma unroll
            for (int ct = 0; ct < 4; ++ct) {
                v8s wh, wl;
                wgather(W, k0 + quad * 8, colbase + ct * 16 + l16, wh, wl);
#pragma unroll
                for (int st = 0; st < 2; ++st) {
                    acc[st][ct] = __builtin_amdgcn_mfma_f32_16x16x32_bf16(al[st], wh, acc[st][ct], 0, 0, 0);
                    acc[st][ct] = __builtin_amdgcn_mfma_f32_16x16x32_bf16(ah[st], wl, acc[st][ct], 0, 0, 0);
                    acc[st][ct] = __builtin_amdgcn_mfma_f32_16x16x32_bf16(ah[st], wh, acc[st][ct], 0, 0, 0);
                }
            }
        }
        if (isK) {
            const int nro = NK - *nexp;
#pragma unroll
            for (int ct = 0; ct < 4; ++ct) {
                const int d = ct * 16 + l16;
                const int j = d >> 1;
                const float freq = exp2f(-(float)(j & 15) * 1.66096404744368f);
                const bool isx = (j < 16), odd = (d & 1);
#pragma unroll
                for (int st = 0; st < 2; ++st)
#pragma unroll
                    for (int r = 0; r < 4; ++r) {
                        const int p = n0 + st * 16 + quad * 4 + r;
                        const int pc = p & 4095;
                        const float tpos = isx ? (float)(pc & 63) : (float)(pc >> 6);
                        float sn, cs;
                        __sincosf(tpos * freq, &sn, &cs);
                        const float x = acc[st][ct][r];
                        const float xp = __shfl_xor(x, 1, 64);
                        float y = odd ? fmaf(x, cs, xp * sn) : fmaf(x, cs, -xp * sn);
                        y = (p < nro) ? y : x;
                        Kb[((size_t)(w * NK + p) << 6) + d] = f2bf(y);
                    }
            }
        } else {
#pragma unroll
            for (int ct = 0; ct < 4; ++ct) {
                const int col = colbase + ct * 16 + l16;
#pragma unroll
                for (int st = 0; st < 2; ++st) {
                    uint2 u = make_uint2(pkbf(acc[st][ct][0], acc[st][ct][1]),
                                         pkbf(acc[st][ct][2], acc[st][ct][3]));
                    *(uint2*)(Vt + (size_t)col * NK + n0 + st * 16 + quad * 4) = u;
                }
            }
        }
    }
}

// ---- flash attention: 1024 blocks = qt(32) x h(4) x s(8); 4 waves x 32 q-rows
// DMA-staged K/V (XOR swizzle), no-max softmax; epilogue = fp32 atomic accumulate
__global__ __launch_bounds__(256) void attn_kernel(
    const unsigned short* __restrict__ Qb, const unsigned short* __restrict__ Kb,
    const unsigned short* __restrict__ Vt, float* __restrict__ Osum,
    float* __restrict__ Lsum)
{
    __shared__ alignas(16) unsigned short Kl[64 * 64];
    __shared__ alignas(16) unsigned short Vl[64 * 64];
    __shared__ alignas(16) unsigned short Pl[4 * 32 * PST];

    const int blk = blockIdx.x;
    const int s = blk & 7, h = (blk >> 3) & 3, qt = blk >> 5;
    const int t = threadIdx.x;
    const int w = t >> 6, lane = t & 63;
    const int quad = lane >> 4, l16 = lane & 15;

    const int q0 = qt * 128 + w * 32;
    v8s qf[2][2];
#pragma unroll
    for (int g = 0; g < 2; ++g) {
        const unsigned short* qr = Qb + ((size_t)(h * NQ + q0 + g * 16 + l16) << 6) + quad * 8;
        qf[g][0] = *(const v8s*)qr;
        qf[g][1] = *(const v8s*)(qr + 32);
    }

    v4f O[4][2];
#pragma unroll
    for (int dt = 0; dt < 4; ++dt)
#pragma unroll
        for (int g = 0; g < 2; ++g) O[dt][g] = v4f{0.f, 0.f, 0.f, 0.f};
    float psum[2] = {0.f, 0.f};

    const unsigned short* Kbase = Kb + (((size_t)h * NK + s * KSPAN) << 6);
    const unsigned short* Vbase = Vt + (size_t)(h * 64) * NK + s * KSPAN;

    const int srow = lane >> 3;            // 0..7
    const int schunk = (lane & 7) ^ srow;  // swizzled 16B chunk
    const int c0off = ((quad ^ (l16 & 7)) * 8);
    const int c1off = c0off ^ 32;
    unsigned short* Pw = &Pl[w * 32 * PST];

    for (int k0 = 0; k0 < KSPAN; k0 += BK) {
        __syncthreads();
#pragma unroll
        for (int half = 0; half < 2; ++half) {
            const int r0 = w * 16 + half * 8;
            dma16(Kbase + ((size_t)(k0 + r0 + srow) << 6) + schunk * 8, &Kl[r0 * 64]);
            dma16(Vbase + (size_t)(r0 + srow) * NK + k0 + schunk * 8, &Vl[r0 * 64]);
        }
        __syncthreads();

        // S^T = K Q^T ; exp2 immediately (no max); stash P[q][k] per-wave
#pragma unroll
        for (int tt = 0; tt < 4; ++tt) {
            const unsigned short* kr = &Kl[(tt * 16 + l16) * 64];
            const v8s kf0 = *(const v8s*)(kr + c0off);
            const v8s kf1 = *(const v8s*)(kr + c1off);
#pragma unroll
            for (int g = 0; g < 2; ++g) {
                v4f a = v4f{0.f, 0.f, 0.f, 0.f};
                a = __builtin_amdgcn_mfma_f32_16x16x32_bf16(kf0, qf[g][0], a, 0, 0, 0);
                a = __builtin_amdgcn_mfma_f32_16x16x32_bf16(kf1, qf[g][1], a, 0, 0, 0);
                const float e0 = __builtin_amdgcn_exp2f(a[0]);
                const float e1 = __builtin_amdgcn_exp2f(a[1]);
                const float e2 = __builtin_amdgcn_exp2f(a[2]);
                const float e3 = __builtin_amdgcn_exp2f(a[3]);
                psum[g] += (e0 + e1) + (e2 + e3);
                *(uint2*)(&Pw[(g * 16 + l16) * PST + tt * 16 + quad * 4]) =
                    make_uint2(pkbf(e0, e1), pkbf(e2, e3));
            }
        }
        __asm__ volatile("s_waitcnt lgkmcnt(0)" ::: "memory");

        v8s pf[2][2];
#pragma unroll
        for (int g = 0; g < 2; ++g) {
            const unsigned short* pr = &Pw[(g * 16 + l16) * PST + quad * 8];
            pf[g][0] = *(const v8s*)pr;
            pf[g][1] = *(const v8s*)(pr + 32);
        }
#pragma unroll
        for (int dt = 0; dt < 4; ++dt) {
            const unsigned short* vr = &Vl[(dt * 16 + l16) * 64];
            const v8s vf0 = *(const v8s*)(vr + c0off);
            const v8s vf1 = *(const v8s*)(vr + c1off);
#pragma unroll
            for (int g = 0; g < 2; ++g) {
                v4f a = O[dt][g];
                a = __builtin_amdgcn_mfma_f32_16x16x32_bf16(vf0, pf[g][0], a, 0, 0, 0);
                a = __builtin_amdgcn_mfma_f32_16x16x32_bf16(vf1, pf[g][1], a, 0, 0, 0);
                O[dt][g] = a;
            }
        }
    }

    // epilogue: atomic-accumulate O (fp32) and l — split-sum is linear
#pragma unroll
    for (int g = 0; g < 2; ++g) {
        const int q = q0 + g * 16 + l16;
        float* orow = Osum + ((size_t)(h * NQ + q) << 6);
#pragma unroll
        for (int dt = 0; dt < 4; ++dt)
#pragma unroll
            for (int r = 0; r < 4; ++r)
                unsafeAtomicAdd(orow + dt * 16 + quad * 4 + r, O[dt][g][r]);
        float p = psum[g];
        p += __shfl_xor(p, 16, 64);
        p += __shfl_xor(p, 32, 64);
        if (quad == 0) unsafeAtomicAdd(Lsum + h * NQ + q, p);
    }
}

// ---- output projection: O/l then x Wo (hi/lo MFMA), 256 blocks x 16 rows
__global__ __launch_bounds__(256) void oproj_kernel(
    const float* __restrict__ Osum, const float* __restrict__ Lsum,
    const float* __restrict__ Wo, const float* __restrict__ bo,
    float* __restrict__ out)
{
    const int t = threadIdx.x, w = t >> 6, lane = t & 63;
    const int quad = lane >> 4, l16 = lane & 15;
    const int n0 = blockIdx.x * 16, colbase = w * 64;
    const int n = n0 + l16;

    float linv[4];
#pragma unroll
    for (int hh = 0; hh < 4; ++hh) linv[hh] = 1.f / Lsum[hh * NQ + n];

    v4f acc[4];
#pragma unroll
    for (int ct = 0; ct < 4; ++ct) {
        const float bb = bo[colbase + ct * 16 + l16];
        acc[ct] = v4f{bb, bb, bb, bb};
    }
#pragma unroll
    for (int k0 = 0; k0 < 256; k0 += 32) {
        const int hh = k0 >> 6;
        const int d0 = (k0 & 63) + quad * 8;
        float av[8];
        const float* ar = Osum + ((size_t)(hh * NQ + n) << 6) + d0;
        *(float4*)av = *(const float4*)ar;
        *(float4*)(av + 4) = *(const float4*)(ar + 4);
#pragma unroll
        for (int j = 0; j < 8; ++j) av[j] *= linv[hh];
        v8s ah, al;
        split8(av, ah, al);
#pragma unroll
        for (int ct = 0; ct < 4; ++ct) {
            v8s wh, wl;
            wgather(Wo, k0 + quad * 8, colbase + ct * 16 + l16, wh, wl);
            acc[ct] = __builtin_amdgcn_mfma_f32_16x16x32_bf16(al, wh, acc[ct], 0, 0, 0);
            acc[ct] = __builtin_amdgcn_mfma_f32_16x16x32_bf16(ah, wl, acc[ct], 0, 0, 0);
            acc[ct] = __builtin_amdgcn_mfma_f32_16x16x32_bf16(ah, wh, acc[ct], 0, 0, 0);
        }
    }
#pragma unroll
    for (int ct = 0; ct < 4; ++ct)
#pragma unroll
        for (int r = 0; r < 4; ++r)
            out[(size_t)(n0 + quad * 4 + r) * 256 + colbase + ct * 16 + l16] = acc[ct][r];
}

extern "C" void kernel_launch(void* const* d_in, const int* in_sizes, int n_in,
                              void* d_out, int out_size, void* d_ws, size_t ws_size,
                              hipStream_t stream) {
    const float* query = (const float*)d_in[0];
    const float* key   = (const float*)d_in[1];
    const float* value = (const float*)d_in[2];
    const float* Wq    = (const float*)d_in[3];
    const float* bq    = (const float*)d_in[4];
    const float* Wk    = (const float*)d_in[5];
    const float* bk    = (const float*)d_in[6];
    const float* Wv    = (const float*)d_in[7];
    const float* bv    = (const float*)d_in[8];
    const float* Wo    = (const float*)d_in[9];
    const float* bo    = (const float*)d_in[10];
    const int*   nex   = (const int*)d_in[11];

    char* ws = (char*)d_ws;
    unsigned short* Qb = (unsigned short*)(ws);                              // 2 MB
    unsigned short* Kb = (unsigned short*)(ws + (size_t)2 * 1024 * 1024);    // 4 MB
    unsigned short* Vt = (unsigned short*)(ws + (size_t)6 * 1024 * 1024);    // 4 MB
    float* Osum        = (float*)(ws + (size_t)10 * 1024 * 1024);            // 4 MB fp32
    float* Lsum        = (float*)(ws + (size_t)14 * 1024 * 1024);            // 64 KB
    float* out         = (float*)d_out;

    hipMemsetAsync(Osum, 0, (size_t)4 * 1024 * 1024 + 64 * 1024, stream);
    qkv_kernel<<<640, 256, 0, stream>>>(query, key, value, Wq, Wk, Wv,
                                        bq, bk, bv, Qb, Kb, Vt, nex);
    attn_kernel<<<1024, 256, 0, stream>>>(Qb, Kb, Vt, Osum, Lsum);
    oproj_kernel<<<256, 256, 0, stream>>>(Osum, Lsum, Wo, bo, out);
}

// Round 9
// 162.106 us; speedup vs baseline: 1.4885x; 1.4885x over previous
//
#include <hip/hip_runtime.h>
#include <hip/hip_bf16.h>

#define NQ 4096
#define NK 8192
#define NSPLIT 8
#define KSPAN (NK / NSPLIT)
#define BK 64
#define PST 72

// 0.125 (1/sqrt(64)) * log2(e): scores in log2 domain; no max subtraction needed
// (|S| <= ~14 in log2 domain, exp2 can't overflow; scale cancels in O/l)
#define QSCALE 0.1803368801111204f

typedef short v8s __attribute__((ext_vector_type(8)));
typedef float v4f __attribute__((ext_vector_type(4)));

static __device__ __forceinline__ unsigned short f2bf(float f) {
    unsigned int u = __float_as_uint(f);
    u = (u + 0x7FFFu + ((u >> 16) & 1u)) >> 16;
    return (unsigned short)u;
}
static __device__ __forceinline__ float bf2f(unsigned short h) {
    return __uint_as_float(((unsigned int)h) << 16);
}
static __device__ __forceinline__ unsigned int pkbf(float a, float b) {
    union { __hip_bfloat162 h; unsigned int u; } cv;
    cv.h = __float22bfloat162_rn(make_float2(a, b));
    return cv.u;
}
static __device__ __forceinline__ void split8(const float* a, v8s& hi, v8s& lo) {
#pragma unroll
    for (int j = 0; j < 8; ++j) {
        unsigned short h = f2bf(a[j]);
        hi[j] = (short)h;
        lo[j] = (short)f2bf(a[j] - bf2f(h));
    }
}
// gather a W^T[col][k0..k0+7] B-fragment from fp32 W[k][col] (ld=256), hi/lo planes
static __device__ __forceinline__ void wgather(const float* __restrict__ W,
                                               int k0, int col, v8s& wh, v8s& wl) {
    float wv[8];
#pragma unroll
    for (int j = 0; j < 8; ++j) wv[j] = W[(size_t)(k0 + j) * 256 + col];
    split8(wv, wh, wl);
}
// async global->LDS, 16B/lane; dest = uniform base + lane*16
static __device__ __forceinline__ void dma16(const unsigned short* g, unsigned short* l) {
    __builtin_amdgcn_global_load_lds(
        (const __attribute__((address_space(1))) unsigned int*)(const void*)g,
        (__attribute__((address_space(3))) unsigned int*)(void*)l, 16, 0, 0);
}

// ---- fused QKV projection, inline W split
// grid 1280: b<256 Q (16 rows), b<768 K (16 rows), else V (16 rows). wave = 64 cols.
__global__ __launch_bounds__(256) void qkv_kernel(
    const float* __restrict__ query, const float* __restrict__ key,
    const float* __restrict__ value,
    const float* __restrict__ Wq, const float* __restrict__ Wk,
    const float* __restrict__ Wv,
    const float* __restrict__ bq, const float* __restrict__ bk,
    const float* __restrict__ bv,
    unsigned short* __restrict__ Qb, unsigned short* __restrict__ Kb,
    unsigned short* __restrict__ Vt, const int* __restrict__ nexp)
{
    const int b = blockIdx.x;
    const int t = threadIdx.x, w = t >> 6, lane = t & 63;
    const int quad = lane >> 4, l16 = lane & 15;
    const int colbase = w * 64;

    if (b < 256) {
        // ---- Q: KD=256
        const int n0 = b * 16;
        v4f acc[4];
#pragma unroll
        for (int ct = 0; ct < 4; ++ct) {
            const float bb = bq[colbase + ct * 16 + l16];
            acc[ct] = v4f{bb, bb, bb, bb};
        }
        const float* arow = query + (size_t)(n0 + l16) * 256 + quad * 8;
#pragma unroll
        for (int k0 = 0; k0 < 256; k0 += 32) {
            float av[8];
            *(float4*)av = *(const float4*)(arow + k0);
            *(float4*)(av + 4) = *(const float4*)(arow + k0 + 4);
            v8s ah, al;
            split8(av, ah, al);
#pragma unroll
            for (int ct = 0; ct < 4; ++ct) {
                v8s wh, wl;
                wgather(Wq, k0 + quad * 8, colbase + ct * 16 + l16, wh, wl);
                acc[ct] = __builtin_amdgcn_mfma_f32_16x16x32_bf16(al, wh, acc[ct], 0, 0, 0);
                acc[ct] = __builtin_amdgcn_mfma_f32_16x16x32_bf16(ah, wl, acc[ct], 0, 0, 0);
                acc[ct] = __builtin_amdgcn_mfma_f32_16x16x32_bf16(ah, wh, acc[ct], 0, 0, 0);
            }
        }
#pragma unroll
        for (int ct = 0; ct < 4; ++ct) {
            const int d = ct * 16 + l16;
            const int j = d >> 1;
            const float freq = exp2f(-(float)(j & 15) * 1.66096404744368f);
            const bool isx = (j < 16), odd = (d & 1);
#pragma unroll
            for (int r = 0; r < 4; ++r) {
                const int p = n0 + quad * 4 + r;
                const float tpos = isx ? (float)(p & 63) : (float)(p >> 6);
                float sn, cs;
                __sincosf(tpos * freq, &sn, &cs);
                const float x = acc[ct][r];
                const float xp = __shfl_xor(x, 1, 64);
                const float y = odd ? fmaf(x, cs, xp * sn) : fmaf(x, cs, -xp * sn);
                Qb[((size_t)(w * NQ + p) << 6) + d] = f2bf(y * QSCALE);
            }
        }
    } else {
        const bool isK = (b < 768);
        const int n0 = (isK ? (b - 256) : (b - 768)) * 16;
        const float* X = isK ? key : value;
        const float* W = isK ? Wk : Wv;
        const float* bias = isK ? bk : bv;
        v4f acc[4];
#pragma unroll
        for (int ct = 0; ct < 4; ++ct) {
            const float bb = bias[colbase + ct * 16 + l16];
            acc[ct] = v4f{bb, bb, bb, bb};
        }
        const float* arow = X + (size_t)(n0 + l16) * 64 + quad * 8;
#pragma unroll
        for (int k0 = 0; k0 < 64; k0 += 32) {
            float av[8];
            *(float4*)av = *(const float4*)(arow + k0);
            *(float4*)(av + 4) = *(const float4*)(arow + k0 + 4);
            v8s ah, al;
            split8(av, ah, al);
#pragma unroll
            for (int ct = 0; ct < 4; ++ct) {
                v8s wh, wl;
                wgather(W, k0 + quad * 8, colbase + ct * 16 + l16, wh, wl);
                acc[ct] = __builtin_amdgcn_mfma_f32_16x16x32_bf16(al, wh, acc[ct], 0, 0, 0);
                acc[ct] = __builtin_amdgcn_mfma_f32_16x16x32_bf16(ah, wl, acc[ct], 0, 0, 0);
                acc[ct] = __builtin_amdgcn_mfma_f32_16x16x32_bf16(ah, wh, acc[ct], 0, 0, 0);
            }
        }
        if (isK) {
            const int nro = NK - *nexp;
#pragma unroll
            for (int ct = 0; ct < 4; ++ct) {
                const int d = ct * 16 + l16;
                const int j = d >> 1;
                const float freq = exp2f(-(float)(j & 15) * 1.66096404744368f);
                const bool isx = (j < 16), odd = (d & 1);
#pragma unroll
                for (int r = 0; r < 4; ++r) {
                    const int p = n0 + quad * 4 + r;
                    const int pc = p & 4095;
                    const float tpos = isx ? (float)(pc & 63) : (float)(pc >> 6);
                    float sn, cs;
                    __sincosf(tpos * freq, &sn, &cs);
                    const float x = acc[ct][r];
                    const float xp = __shfl_xor(x, 1, 64);
                    float y = odd ? fmaf(x, cs, xp * sn) : fmaf(x, cs, -xp * sn);
                    y = (p < nro) ? y : x;
                    Kb[((size_t)(w * NK + p) << 6) + d] = f2bf(y);
                }
            }
        } else {
#pragma unroll
            for (int ct = 0; ct < 4; ++ct) {
                const int col = colbase + ct * 16 + l16;
                uint2 u = make_uint2(pkbf(acc[ct][0], acc[ct][1]),
                                     pkbf(acc[ct][2], acc[ct][3]));
                *(uint2*)(Vt + (size_t)col * NK + n0 + quad * 4) = u;
            }
        }
    }
}

// ---- flash attention (exact R5 shape): 1024 blocks = qt(32) x h(4) x s(8);
// 4 waves x 32 q-rows; DMA-staged K/V (XOR swizzle), no-max softmax
__global__ __launch_bounds__(256) void attn_kernel(
    const unsigned short* __restrict__ Qb, const unsigned short* __restrict__ Kb,
    const unsigned short* __restrict__ Vt, unsigned short* __restrict__ Opart,
    float* __restrict__ Lbuf)
{
    __shared__ alignas(16) unsigned short Kl[64 * 64];
    __shared__ alignas(16) unsigned short Vl[64 * 64];
    __shared__ alignas(16) unsigned short Pl[4 * 32 * PST];

    const int blk = blockIdx.x;
    const int s = blk & 7, h = (blk >> 3) & 3, qt = blk >> 5;
    const int t = threadIdx.x;
    const int w = t >> 6, lane = t & 63;
    const int quad = lane >> 4, l16 = lane & 15;

    const int q0 = qt * 128 + w * 32;
    v8s qf[2][2];
#pragma unroll
    for (int g = 0; g < 2; ++g) {
        const unsigned short* qr = Qb + ((size_t)(h * NQ + q0 + g * 16 + l16) << 6) + quad * 8;
        qf[g][0] = *(const v8s*)qr;
        qf[g][1] = *(const v8s*)(qr + 32);
    }

    v4f O[4][2];
#pragma unroll
    for (int dt = 0; dt < 4; ++dt)
#pragma unroll
        for (int g = 0; g < 2; ++g) O[dt][g] = v4f{0.f, 0.f, 0.f, 0.f};
    float psum[2] = {0.f, 0.f};

    const unsigned short* Kbase = Kb + (((size_t)h * NK + s * KSPAN) << 6);
    const unsigned short* Vbase = Vt + (size_t)(h * 64) * NK + s * KSPAN;

    const int srow = lane >> 3;            // 0..7
    const int schunk = (lane & 7) ^ srow;  // swizzled 16B chunk
    const int c0off = ((quad ^ (l16 & 7)) * 8);
    const int c1off = c0off ^ 32;
    unsigned short* Pw = &Pl[w * 32 * PST];

    for (int k0 = 0; k0 < KSPAN; k0 += BK) {
        __syncthreads();
#pragma unroll
        for (int half = 0; half < 2; ++half) {
            const int r0 = w * 16 + half * 8;
            dma16(Kbase + ((size_t)(k0 + r0 + srow) << 6) + schunk * 8, &Kl[r0 * 64]);
            dma16(Vbase + (size_t)(r0 + srow) * NK + k0 + schunk * 8, &Vl[r0 * 64]);
        }
        __syncthreads();

        // S^T = K Q^T ; exp2 immediately (no max); stash P[q][k] per-wave
#pragma unroll
        for (int tt = 0; tt < 4; ++tt) {
            const unsigned short* kr = &Kl[(tt * 16 + l16) * 64];
            const v8s kf0 = *(const v8s*)(kr + c0off);
            const v8s kf1 = *(const v8s*)(kr + c1off);
#pragma unroll
            for (int g = 0; g < 2; ++g) {
                v4f a = v4f{0.f, 0.f, 0.f, 0.f};
                a = __builtin_amdgcn_mfma_f32_16x16x32_bf16(kf0, qf[g][0], a, 0, 0, 0);
                a = __builtin_amdgcn_mfma_f32_16x16x32_bf16(kf1, qf[g][1], a, 0, 0, 0);
                const float e0 = __builtin_amdgcn_exp2f(a[0]);
                const float e1 = __builtin_amdgcn_exp2f(a[1]);
                const float e2 = __builtin_amdgcn_exp2f(a[2]);
                const float e3 = __builtin_amdgcn_exp2f(a[3]);
                psum[g] += (e0 + e1) + (e2 + e3);
                *(uint2*)(&Pw[(g * 16 + l16) * PST + tt * 16 + quad * 4]) =
                    make_uint2(pkbf(e0, e1), pkbf(e2, e3));
            }
        }
        __asm__ volatile("s_waitcnt lgkmcnt(0)" ::: "memory");

        v8s pf[2][2];
#pragma unroll
        for (int g = 0; g < 2; ++g) {
            const unsigned short* pr = &Pw[(g * 16 + l16) * PST + quad * 8];
            pf[g][0] = *(const v8s*)pr;
            pf[g][1] = *(const v8s*)(pr + 32);
        }
#pragma unroll
        for (int dt = 0; dt < 4; ++dt) {
            const unsigned short* vr = &Vl[(dt * 16 + l16) * 64];
            const v8s vf0 = *(const v8s*)(vr + c0off);
            const v8s vf1 = *(const v8s*)(vr + c1off);
#pragma unroll
            for (int g = 0; g < 2; ++g) {
                v4f a = O[dt][g];
                a = __builtin_amdgcn_mfma_f32_16x16x32_bf16(vf0, pf[g][0], a, 0, 0, 0);
                a = __builtin_amdgcn_mfma_f32_16x16x32_bf16(vf1, pf[g][1], a, 0, 0, 0);
                O[dt][g] = a;
            }
        }
    }

#pragma unroll
    for (int g = 0; g < 2; ++g) {
        float p = psum[g];
        p += __shfl_xor(p, 16, 64);
        p += __shfl_xor(p, 32, 64);
        psum[g] = p;
    }
    unsigned short* Ob = Opart + (size_t)blk * 8192;
#pragma unroll
    for (int g = 0; g < 2; ++g) {
        const int row = w * 32 + g * 16 + l16;
#pragma unroll
        for (int dt = 0; dt < 4; ++dt) {
            uint2 u = make_uint2(pkbf(O[dt][g][0], O[dt][g][1]),
                                 pkbf(O[dt][g][2], O[dt][g][3]));
            *(uint2*)(Ob + row * 64 + dt * 16 + quad * 4) = u;
        }
        if (quad == 0) Lbuf[blk * 128 + row] = psum[g];
    }
}

// ---- output projection: split-sum in VALU first, then 1x MFMA; fused 1/l
__global__ __launch_bounds__(256) void oproj_kernel(
    const unsigned short* __restrict__ Opart, const float* __restrict__ Lbuf,
    const float* __restrict__ Wo, const float* __restrict__ bo,
    float* __restrict__ out)
{
    const int t = threadIdx.x, w = t >> 6, lane = t & 63;
    const int quad = lane >> 4, l16 = lane & 15;
    const int n0 = blockIdx.x * 16, colbase = w * 64;
    const int qt32 = (n0 >> 7) * 32;
    const int rbase = n0 & 127;

    float linv[4];
#pragma unroll
    for (int hh = 0; hh < 4; ++hh) {
        float ls = 0.f;
#pragma unroll
        for (int sp = 0; sp < NSPLIT; ++sp)
            ls += Lbuf[(qt32 + hh * 8 + sp) * 128 + rbase + l16];
        linv[hh] = 1.f / ls;
    }
    v4f acc[4];
#pragma unroll
    for (int ct = 0; ct < 4; ++ct) {
        const float bb = bo[colbase + ct * 16 + l16];
        acc[ct] = v4f{bb, bb, bb, bb};
    }
#pragma unroll
    for (int k0 = 0; k0 < 256; k0 += 32) {
        const int hh = k0 >> 6;
        const int d0 = (k0 & 63) + quad * 8;
        float av[8] = {0.f, 0.f, 0.f, 0.f, 0.f, 0.f, 0.f, 0.f};
#pragma unroll
        for (int sp = 0; sp < NSPLIT; ++sp) {
            const v8s A = *(const v8s*)(Opart + (size_t)(qt32 + hh * 8 + sp) * 8192
                                        + (rbase + l16) * 64 + d0);
#pragma unroll
            for (int j = 0; j < 8; ++j) av[j] += bf2f((unsigned short)A[j]);
        }
#pragma unroll
        for (int j = 0; j < 8; ++j) av[j] *= linv[hh];
        v8s ah, al;
        split8(av, ah, al);
#pragma unroll
        for (int ct = 0; ct < 4; ++ct) {
            v8s wh, wl;
            wgather(Wo, k0 + quad * 8, colbase + ct * 16 + l16, wh, wl);
            acc[ct] = __builtin_amdgcn_mfma_f32_16x16x32_bf16(al, wh, acc[ct], 0, 0, 0);
            acc[ct] = __builtin_amdgcn_mfma_f32_16x16x32_bf16(ah, wl, acc[ct], 0, 0, 0);
            acc[ct] = __builtin_amdgcn_mfma_f32_16x16x32_bf16(ah, wh, acc[ct], 0, 0, 0);
        }
    }
#pragma unroll
    for (int ct = 0; ct < 4; ++ct)
#pragma unroll
        for (int r = 0; r < 4; ++r)
            out[(size_t)(n0 + quad * 4 + r) * 256 + colbase + ct * 16 + l16] = acc[ct][r];
}

extern "C" void kernel_launch(void* const* d_in, const int* in_sizes, int n_in,
                              void* d_out, int out_size, void* d_ws, size_t ws_size,
                              hipStream_t stream) {
    const float* query = (const float*)d_in[0];
    const float* key   = (const float*)d_in[1];
    const float* value = (const float*)d_in[2];
    const float* Wq    = (const float*)d_in[3];
    const float* bq    = (const float*)d_in[4];
    const float* Wk    = (const float*)d_in[5];
    const float* bk    = (const float*)d_in[6];
    const float* Wv    = (const float*)d_in[7];
    const float* bv    = (const float*)d_in[8];
    const float* Wo    = (const float*)d_in[9];
    const float* bo    = (const float*)d_in[10];
    const int*   nex   = (const int*)d_in[11];

    char* ws = (char*)d_ws;
    unsigned short* Qb    = (unsigned short*)(ws);                              // 2 MB
    unsigned short* Kb    = (unsigned short*)(ws + (size_t)2 * 1024 * 1024);    // 4 MB
    unsigned short* Vt    = (unsigned short*)(ws + (size_t)6 * 1024 * 1024);    // 4 MB
    unsigned short* Opart = (unsigned short*)(ws + (size_t)10 * 1024 * 1024);   // 16 MB bf16
    float* Lbuf           = (float*)(ws + (size_t)26 * 1024 * 1024);            // 512 KB
    float* out            = (float*)d_out;

    qkv_kernel<<<1280, 256, 0, stream>>>(query, key, value, Wq, Wk, Wv,
                                         bq, bk, bv, Qb, Kb, Vt, nex);
    attn_kernel<<<1024, 256, 0, stream>>>(Qb, Kb, Vt, Opart, Lbuf);
    oproj_kernel<<<256, 256, 0, stream>>>(Opart, Lbuf, Wo, bo, out);
}